// Round 8
// baseline (240.191 us; speedup 1.0000x reference)
//
#include <hip/hip_runtime.h>

// arHOCA: L=200 positions, Q=21 alphabet, H=128 hidden, B=256 batch.
// x is one-hot => all "x @ W" contractions are gather-sums over idx[b,l].
//
// DCA mask (faithful to reference): mask loop is `for i in range(Q)`, so only
// row-blocks 1..20 / col-blocks 0..19 are active; mask[d,c]=1 iff blk(c)<blk(d).
// => out_dca[b,j] = sum_{l=j/Q+1}^{20} DW[l*Q+idx[b,l], j].
//
// ws layout: idxT [200][256] int (204800B) | h1 [199][256][128] f32 (26083328B)
//            | h2T [199][128][256] f32 (26083328B)  => 52371456 B total.

#define Lc   200
#define Qc   21
#define Hc   128
#define Bc   256
#define LQc  4200
#define LM1c 199

// ---------------- K0: idxT[l][b] = argmax_c x[b,l,c] ----------------
__global__ __launch_bounds__(256) void k_idx(const float* __restrict__ x,
                                             int* __restrict__ idxT) {
    const int l = blockIdx.x;       // 0..199
    const int b = threadIdx.x;      // 0..255
    const float* p = x + ((size_t)b * Lc + l) * Qc;
    int id = 0;
#pragma unroll
    for (int c = 0; c < Qc; ++c) id = (p[c] > 0.5f) ? c : id;
    idxT[l * Bc + b] = id;          // coalesced store
}

// ---------------- K1: DCA gather + bias + out0 (w0+b0) ----------------
// out[b, j] = bias[j] + sum_{l = j/Q+1 .. 20} DW[l*Q+idx[b,l], j]  (+ w0+b0 for j<Q)
__global__ __launch_bounds__(256) void k_dca(const float* __restrict__ DW,
                                             const float* __restrict__ bias,
                                             const float* __restrict__ w0,
                                             const float* __restrict__ b0,
                                             const int* __restrict__ idxT,
                                             float* __restrict__ out) {
    const int b = blockIdx.x / 5, chunk = blockIdx.x % 5;
    const int j0 = chunk * 1024 + threadIdx.x * 4;
    if (j0 >= LQc) return;
    float a[4];
    const float4 bv = *(const float4*)(bias + j0);
    a[0] = bv.x; a[1] = bv.y; a[2] = bv.z; a[3] = bv.w;
    if (j0 < Qc) {
#pragma unroll
        for (int e = 0; e < 4; ++e) {
            int j = j0 + e;
            if (j < Qc) a[e] += w0[j] + b0[j];
        }
    }
    if (j0 < (Qc - 1) * Qc) {
        const int lmin = j0 / Qc + 1;
        for (int l = lmin; l < Qc; ++l) {
            const int iv = idxT[l * Bc + b];
            const float4 v = *(const float4*)(DW + (size_t)(l * Qc + iv) * LQc + j0);
            const int thr = l * Qc;  // contribute iff j < l*Q
            a[0] += (j0     < thr) ? v.x : 0.f;
            a[1] += (j0 + 1 < thr) ? v.y : 0.f;
            a[2] += (j0 + 2 < thr) ? v.z : 0.f;
            a[3] += (j0 + 3 < thr) ? v.w : 0.f;
        }
    }
    float4 o = {a[0], a[1], a[2], a[3]};
    *(float4*)(out + (size_t)b * LQc + j0) = o;
}

// ---------------- K2: 64-batch block gather — CU-level L1 reuse ----------------
// h1[l][b][h] = lrelu(sum_{lp<=l} W1[l, lp*Q+idx[b,lp], h] + b1[l,h])
// Block = (l, 64-batch group), 512 threads (8 waves). Lane owns 4 consecutive
// batches x 4 h (hq quad); per lp the block touches <=21 rows (10.5 KB): first
// wave misses to L2, remaining 7 waves hit L1 -> L2 traffic ~0.8 GB (vs 2.6).
// idx int4-packed (4 batches / 1 load), window J1..J3 prefetched >=1 body
// ahead; 2-deep unroll keeps 8 row-loads in flight per wave at ~100 VGPR.
// XCD map: r = s*8 + (bid&7): balanced, all 4 groups of one l on one XCD.
__global__ __launch_bounds__(512, 4) void k_h1(const float* __restrict__ W1,
                                               const float* __restrict__ b1,
                                               const int* __restrict__ idxT,
                                               float* __restrict__ h1) {
    const int bid = blockIdx.x;            // 0..799
    const int xcd = bid & 7;
    const int u   = bid >> 3;              // 0..99
    const int s   = u >> 2, g = u & 3;     // s 0..24, g 0..3
    const int r   = s * 8 + xcd;
    if (r >= LM1c) return;                 // 4 idle blocks
    const int l = 198 - r;                 // long blocks spread over all XCDs
    const int t = threadIdx.x;
    const int w = t >> 6, lane = t & 63;
    const int p = lane >> 5;               // half-wave
    const int hq = lane & 31;              // h-quad: h = hq*4..hq*4+3
    const int bbase = g * 64 + w * 8 + p * 4;  // lane's 4 batches

    const float* Wq = W1 + (size_t)l * (LQc * Hc) + hq * 4;
    const int* i0 = idxT + bbase;          // int4 at i0[lp*Bc] = idx of 4 batches

    float4 acc0 = {0,0,0,0}, acc1 = {0,0,0,0}, acc2 = {0,0,0,0}, acc3 = {0,0,0,0};
    float4 va0, va1, va2, va3, vb0, vb1, vb2, vb3;

#define IDX4(lpv) (*(const int4*)(i0 + (lpv) * Bc))
#define ROW(lpv, ia) (*(const float4*)(Wq + (size_t)((lpv) * Qc + (ia)) * Hc))
#define ADD4(A, V) { A.x += V.x; A.y += V.y; A.z += V.z; A.w += V.w; }

    const int4 J0 = IDX4(0);
    int4 J1 = IDX4((1 <= l) ? 1 : 0);
    int4 J2 = IDX4((2 <= l) ? 2 : 0);
    int4 J3 = IDX4((3 <= l) ? 3 : 0);

    va0 = ROW(0, J0.x); va1 = ROW(0, J0.y); va2 = ROW(0, J0.z); va3 = ROW(0, J0.w);

    int lp = 0;
    while (lp + 1 <= l) {
        const int4 K4 = IDX4((lp + 4 <= l) ? lp + 4 : 0);
        const int4 K5 = IDX4((lp + 5 <= l) ? lp + 5 : 0);
        // issue set B (lp+1, real); J1 was loaded >=1 body ago
        vb0 = ROW(lp + 1, J1.x); vb1 = ROW(lp + 1, J1.y);
        vb2 = ROW(lp + 1, J1.z); vb3 = ROW(lp + 1, J1.w);
        ADD4(acc0, va0) ADD4(acc1, va1) ADD4(acc2, va2) ADD4(acc3, va3)
        // issue set A (lp+2; dummy reloads lp-index clamped row, never consumed)
        const int lp2 = (lp + 2 <= l) ? lp + 2 : 0;
        va0 = ROW(lp2, J2.x); va1 = ROW(lp2, J2.y);
        va2 = ROW(lp2, J2.z); va3 = ROW(lp2, J2.w);
        ADD4(acc0, vb0) ADD4(acc1, vb1) ADD4(acc2, vb2) ADD4(acc3, vb3)
        J1 = J3; J2 = K4; J3 = K5;
        lp += 2;
    }
    if (lp == l) { ADD4(acc0, va0) ADD4(acc1, va1) ADD4(acc2, va2) ADD4(acc3, va3) }
#undef IDX4
#undef ROW
#undef ADD4

    const float4 bb = *(const float4*)(b1 + l * Hc + hq * 4);
    float* outp = h1 + ((size_t)l * Bc + bbase) * Hc + hq * 4;
#define STORE(i, C) { float4 rr; \
    rr.x = C.x + bb.x; rr.y = C.y + bb.y; rr.z = C.z + bb.z; rr.w = C.w + bb.w; \
    rr.x = (rr.x >= 0.f) ? rr.x : 0.1f * rr.x; rr.y = (rr.y >= 0.f) ? rr.y : 0.1f * rr.y; \
    rr.z = (rr.z >= 0.f) ? rr.z : 0.1f * rr.z; rr.w = (rr.w >= 0.f) ? rr.w : 0.1f * rr.w; \
    *(float4*)(outp + (size_t)(i) * Hc) = rr; }
    STORE(0, acc0) STORE(1, acc1) STORE(2, acc2) STORE(3, acc3)
#undef STORE
}

// ---------------- K3: h2T[l][n][b] = lrelu(sum_k h1[l][b][k] * W2[l][k][n] + b2[l][n]) ----------------
// fp32 tiled GEMM: M=128 (batch half), N=128, K=128 in 8 steps of 16. 8x8 reg tile/thread.
// A-side ([b][k] row-major) is transposed into padded LDS during staging.
__global__ __launch_bounds__(256) void k_h2(const float* __restrict__ h1,
                                            const float* __restrict__ W2,
                                            const float* __restrict__ b2,
                                            float* __restrict__ h2T) {
    const int l = blockIdx.x >> 1;
    const int bbase = (blockIdx.x & 1) * 128;
    const int t = threadIdx.x;
    const int tx = t & 15, ty = t >> 4;
    __shared__ float As[16][132];
    __shared__ float Bs[16][Hc];
    __shared__ float Ts[32][Hc];
    float acc[8][8];
#pragma unroll
    for (int i = 0; i < 8; ++i)
#pragma unroll
        for (int j = 0; j < 8; ++j) acc[i][j] = 0.f;
    const int skk = t >> 4, sms = (t & 15) * 8;
    const int au = t >> 2, av4 = (t & 3) * 4;   // A-stage: m=au(+64), k-quad av4
    const float* h1l = h1 + ((size_t)l * Bc + bbase) * Hc;
    const float* W2l = W2 + (size_t)l * Hc * Hc;
    for (int ks = 0; ks < 8; ++ks) {
        const float4 a0 = *(const float4*)(h1l + (size_t)au * Hc + ks * 16 + av4);
        const float4 a1 = *(const float4*)(h1l + (size_t)(au + 64) * Hc + ks * 16 + av4);
        const int kb = ks * 16 + skk;
        *(float4*)&Bs[skk][sms]     = *(const float4*)(W2l + (size_t)kb * Hc + sms);
        *(float4*)&Bs[skk][sms + 4] = *(const float4*)(W2l + (size_t)kb * Hc + sms + 4);
        As[av4 + 0][au] = a0.x; As[av4 + 1][au] = a0.y;
        As[av4 + 2][au] = a0.z; As[av4 + 3][au] = a0.w;
        As[av4 + 0][au + 64] = a1.x; As[av4 + 1][au + 64] = a1.y;
        As[av4 + 2][au + 64] = a1.z; As[av4 + 3][au + 64] = a1.w;
        __syncthreads();
#pragma unroll
        for (int k = 0; k < 16; ++k) {
            float avr[8], bvr[8];
            *(float4*)&avr[0] = *(const float4*)&As[k][ty * 8];
            *(float4*)&avr[4] = *(const float4*)&As[k][ty * 8 + 4];
            *(float4*)&bvr[0] = *(const float4*)&Bs[k][tx * 8];
            *(float4*)&bvr[4] = *(const float4*)&Bs[k][tx * 8 + 4];
#pragma unroll
            for (int i = 0; i < 8; ++i)
#pragma unroll
                for (int j = 0; j < 8; ++j) acc[i][j] += avr[i] * bvr[j];
        }
        __syncthreads();
    }
    float bz[8];
    *(float4*)&bz[0] = *(const float4*)(b2 + l * Hc + tx * 8);
    *(float4*)&bz[4] = *(const float4*)(b2 + l * Hc + tx * 8 + 4);
    float res[8][8];
#pragma unroll
    for (int i = 0; i < 8; ++i)
#pragma unroll
        for (int j = 0; j < 8; ++j) {
            float v = acc[i][j] + bz[j];
            res[i][j] = (v >= 0.f) ? v : 0.1f * v;
        }
    // transpose-store via LDS in 4 chunks of 32 n-rows: h2T[l][n][bbase+m]
    for (int c = 0; c < 4; ++c) {
        if ((tx >> 2) == c) {
#pragma unroll
            for (int i = 0; i < 8; ++i)
#pragma unroll
                for (int j = 0; j < 8; ++j) Ts[(tx & 3) * 8 + j][ty * 8 + i] = res[i][j];
        }
        __syncthreads();
        const int r = t >> 3, m2 = (t & 7) * 16;
        float* dst = h2T + ((size_t)l * Hc + c * 32 + r) * Bc + bbase + m2;
#pragma unroll
        for (int u = 0; u < 4; ++u) *(float4*)(dst + u * 4) = *(const float4*)&Ts[r][m2 + u * 4];
        __syncthreads();
    }
}

// ---------------- K4: out[b, l+1, q] += sum_k h2T[l][k][b] * Wout[l][k][q] + bout[l][q] ----------------
__global__ __launch_bounds__(128) void k_out(const float* __restrict__ h2T,
                                             const float* __restrict__ Wout,
                                             const float* __restrict__ bout,
                                             float* __restrict__ out) {
    const int l = blockIdx.x >> 1;
    const int bh = blockIdx.x & 1;
    const int t = threadIdx.x;  // 0..127
    __shared__ float wl[Hc * Qc];
    __shared__ float bl[Qc];
    const float* wsrc = Wout + (size_t)l * Hc * Qc;
    for (int i = t; i < Hc * Qc; i += 128) wl[i] = wsrc[i];
    if (t < Qc) bl[t] = bout[l * Qc + t];
    __syncthreads();
    const int b = bh * 128 + t;
    float acc[Qc];
#pragma unroll
    for (int q = 0; q < Qc; ++q) acc[q] = bl[q];
    const float* h2l = h2T + (size_t)l * Hc * Bc + b;
    for (int k = 0; k < Hc; ++k) {
        const float av = h2l[(size_t)k * Bc];
        const float* wr = &wl[k * Qc];
#pragma unroll
        for (int q = 0; q < Qc; ++q) acc[q] += av * wr[q];
    }
    float* op = out + ((size_t)b * Lc + (l + 1)) * Qc;
#pragma unroll
    for (int q = 0; q < Qc; ++q) op[q] += acc[q];
}

extern "C" void kernel_launch(void* const* d_in, const int* in_sizes, int n_in,
                              void* d_out, int out_size, void* d_ws, size_t ws_size,
                              hipStream_t stream) {
    const float* x    = (const float*)d_in[0];
    const float* bias = (const float*)d_in[1];
    const float* DW   = (const float*)d_in[2];
    const float* w0   = (const float*)d_in[3];
    const float* b0   = (const float*)d_in[4];
    const float* W1   = (const float*)d_in[5];
    const float* b1   = (const float*)d_in[6];
    const float* W2   = (const float*)d_in[7];
    const float* b2   = (const float*)d_in[8];
    const float* Wout = (const float*)d_in[9];
    const float* bout = (const float*)d_in[10];
    float* out = (float*)d_out;

    int*   idxT = (int*)d_ws;
    float* h1   = (float*)((char*)d_ws + 204800);
    float* h2T  = (float*)((char*)d_ws + 204800 + 26083328);

    k_idx<<<Lc, 256, 0, stream>>>(x, idxT);
    k_dca<<<Bc * 5, 256, 0, stream>>>(DW, bias, w0, b0, idxT, out);
    k_h1<<<800, 512, 0, stream>>>(W1, b1, idxT, h1);
    k_h2<<<LM1c * 2, 256, 0, stream>>>(h1, W2, b2, h2T);
    k_out<<<LM1c * 2, 128, 0, stream>>>(h2T, Wout, bout, out);
}